// Round 8
// baseline (979.292 us; speedup 1.0000x reference)
//
#include <hip/hip_runtime.h>
#include <hip/hip_bf16.h>

// SwinMLP block, fp32 in/out, bf16 MFMA internals.
//   1) cvt_t: w1 -> w1t (bf16, NxK), w2 -> w2t (bf16, NxK)
//   2) fused_pre: LN1 + per-head 32x32 spatial mix + residual -> x2 (d_out)
//      + LN2(x2) -> y (bf16, ws)
//   3) gemm1: z = gelu(y @ w1 + b1)   [M-split A/B ablation]
//   4) gemm2: d_out = x2 + z @ w2 + b2 [M-split A/B ablation]
//
// R7 post-mortem: write-amp fixed (742->401MB) but dur flat; bank-conflict
// counter IDENTICAL across 3 LDS layouts -> b128 reads at 64B row stride are
// already bank-balanced; swizzle was decoration. Per-tile 4970cy vs 2600
// accounted. R8: WITHIN-PROBE ABLATION (M-split halves, per-dispatch rocprof):
//   gemm1 A=control(R7)  B=control-minus-swizzle  -> is swizzle null?
//   gemm2 A=control(R7)  B=gemm2s: BK=64 2-slot classic dbuf, vmcnt(0) AFTER
//         compute, ONE barrier/64k (4x fewer syncs; needs q^=row&7 swizzle
//         since 128B row stride IS the pathological case)

typedef __bf16 bf16x8 __attribute__((ext_vector_type(8)));
typedef float f32x4 __attribute__((ext_vector_type(4)));

constexpr int CDIM = 512;
constexpr int HID = 2048;
constexpr int MROWS = 32 * 3136;  // 100352 = 392 * 256
constexpr int MHALF = MROWS / 2;  // 50176 = 196 * 256
constexpr float LN_EPS = 1e-5f;

static __device__ __forceinline__ float gelu_tanh(float x) {
  const float u = 0.7978845608028654f * fmaf(0.044715f * x * x, x, x);
  const float e = __expf(2.0f * u);
  return 0.5f * x * (2.0f - 2.0f / (e + 1.0f));
}

static __device__ __forceinline__ void load_lds16(const void* g, void* l) {
  __builtin_amdgcn_global_load_lds((__attribute__((address_space(1))) void*)g,
                                   (__attribute__((address_space(3))) void*)l,
                                   16, 0, 0);
}

// ---- transpose fp32 src[KD][ND] -> bf16 dst[ND][KD], 64x64 LDS tiles ----
template <int KD, int ND>
__global__ __launch_bounds__(256) void cvt_t(const float* __restrict__ src,
                                             __hip_bfloat16* __restrict__ dst) {
  __shared__ float tl[64][65];
  const int t = threadIdx.x;
  constexpr int NTN = ND / 64;
  const int k0 = (blockIdx.x / NTN) * 64;
  const int n0 = (blockIdx.x % NTN) * 64;
  const int c4 = (t & 15) * 4;
  const int r = t >> 4;
#pragma unroll
  for (int j = 0; j < 4; ++j) {
    const int kk = r + j * 16;
    const float4 v = *(const float4*)&src[(size_t)(k0 + kk) * ND + n0 + c4];
    tl[c4 + 0][kk] = v.x;
    tl[c4 + 1][kk] = v.y;
    tl[c4 + 2][kk] = v.z;
    tl[c4 + 3][kk] = v.w;
  }
  __syncthreads();
#pragma unroll
  for (int j = 0; j < 4; ++j) {
    const int nn = r + j * 16;
    __hip_bfloat16 o[4];
#pragma unroll
    for (int c = 0; c < 4; ++c) o[c] = __float2bfloat16(tl[nn][c4 + c]);
    *(uint2*)&dst[(size_t)(n0 + nn) * KD + k0 + c4] = *(const uint2*)o;
  }
}

// ---------------- fused LN1 + spatial mix + residual + LN2 ----------------
__global__ __launch_bounds__(256) void fused_pre(
    const float* __restrict__ x, const float* __restrict__ g1,
    const float* __restrict__ b1, const float* __restrict__ wsp,
    const float* __restrict__ g2, const float* __restrict__ b2,
    float* __restrict__ x2out, __hip_bfloat16* __restrict__ yout) {
  __shared__ float lnbuf[CDIM];
  __shared__ float red[8];

  const int t = threadIdx.x;
  const int lane = t & 63;
  const int w = t >> 6;
  const int c0 = 2 * t;
  const int hd = c0 >> 5, e0 = c0 & 31;

  float wc0[32], wc1[32];
#pragma unroll
  for (int d = 0; d < 32; ++d) {
    const float2 wv = *(const float2*)&wsp[(hd * 32 + d) * 32 + e0];
    wc0[d] = wv.x;
    wc1[d] = wv.y;
  }
  const float2 g1v = *(const float2*)&g1[c0];
  const float2 b1v = *(const float2*)&b1[c0];
  const float2 g2v = *(const float2*)&g2[c0];
  const float2 b2v = *(const float2*)&b2[c0];

  for (int r = blockIdx.x; r < MROWS; r += gridDim.x) {
    const float2 xv = *(const float2*)&x[(size_t)r * CDIM + c0];

    float s = xv.x + xv.y, ss = xv.x * xv.x + xv.y * xv.y;
#pragma unroll
    for (int off = 32; off; off >>= 1) {
      s += __shfl_down(s, off);
      ss += __shfl_down(ss, off);
    }
    if (lane == 0) { red[w * 2] = s; red[w * 2 + 1] = ss; }
    __syncthreads();
    s = red[0] + red[2] + red[4] + red[6];
    ss = red[1] + red[3] + red[5] + red[7];
    float mu = s * (1.0f / CDIM);
    float var = ss * (1.0f / CDIM) - mu * mu;
    float rs = rsqrtf(var + LN_EPS);
    lnbuf[c0] = (xv.x - mu) * rs * g1v.x + b1v.x;
    lnbuf[c0 + 1] = (xv.y - mu) * rs * g1v.y + b1v.y;
    __syncthreads();

    float h0 = 0.f, h1 = 0.f;
#pragma unroll
    for (int d = 0; d < 32; ++d) {
      const float lv = lnbuf[hd * 32 + d];
      h0 = fmaf(lv, wc0[d], h0);
      h1 = fmaf(lv, wc1[d], h1);
    }
    const float a0 = xv.x + h0, a1 = xv.y + h1;
    float2 av;
    av.x = a0;
    av.y = a1;
    *(float2*)&x2out[(size_t)r * CDIM + c0] = av;

    s = a0 + a1;
    ss = a0 * a0 + a1 * a1;
#pragma unroll
    for (int off = 32; off; off >>= 1) {
      s += __shfl_down(s, off);
      ss += __shfl_down(ss, off);
    }
    if (lane == 0) { red[w * 2] = s; red[w * 2 + 1] = ss; }
    __syncthreads();
    s = red[0] + red[2] + red[4] + red[6];
    ss = red[1] + red[3] + red[5] + red[7];
    mu = s * (1.0f / CDIM);
    var = ss * (1.0f / CDIM) - mu * mu;
    rs = rsqrtf(var + LN_EPS);
    __hip_bfloat162 yv;
    yv.x = __float2bfloat16((a0 - mu) * rs * g2v.x + b2v.x);
    yv.y = __float2bfloat16((a1 - mu) * rs * g2v.y + b2v.y);
    *(__hip_bfloat162*)&yout[(size_t)r * CDIM + c0] = yv;
    __syncthreads();
  }
}

// ---- shared epilogue: LDS bounce, full-line coalesced writes (R7-verified) --
template <int N, bool GELU>
static __device__ __forceinline__ void epilogue(const f32x4 (&acc)[8][4],
                                                char* smb, int tid, int lane,
                                                int wm, int wn, size_t am0,
                                                int bn0,
                                                const float* __restrict__ bias,
                                                __hip_bfloat16* __restrict__ zout,
                                                float* __restrict__ fout) {
  const int cr = (lane >> 4) * 4;
  const int cc = lane & 15;
  if constexpr (GELU) {
    __syncthreads();
    __hip_bfloat16* ot = (__hip_bfloat16*)smb;
#pragma unroll
    for (int n = 0; n < 4; ++n) {
      const int col = wn * 64 + n * 16 + cc;
      const float bv = bias[bn0 + col];
#pragma unroll
      for (int m = 0; m < 8; ++m) {
        const int row = wm * 128 + m * 16 + cr;
#pragma unroll
        for (int j = 0; j < 4; ++j)
          ot[(row + j) * 256 + col] =
              __float2bfloat16(gelu_tanh(acc[m][n][j] + bv));
      }
    }
    __syncthreads();
#pragma unroll
    for (int it = 0; it < 16; ++it) {
      const int seg = it * 512 + tid;
      const int row = seg >> 5, cs = seg & 31;
      const uint4 v = *(const uint4*)(smb + seg * 16);
      *(uint4*)&zout[(am0 + row) * N + bn0 + cs * 8] = v;
    }
  } else {
    float* ot = (float*)smb;
#pragma unroll
    for (int p = 0; p < 2; ++p) {
      __syncthreads();
      if (wm == p) {
#pragma unroll
        for (int n = 0; n < 4; ++n) {
          const int col = wn * 64 + n * 16 + cc;
          const float bv = bias[bn0 + col];
#pragma unroll
          for (int m = 0; m < 8; ++m) {
            const int rl = m * 16 + cr;
#pragma unroll
            for (int j = 0; j < 4; ++j)
              ot[(rl + j) * 256 + col] = acc[m][n][j] + bv;
          }
        }
      }
      __syncthreads();
#pragma unroll
      for (int it = 0; it < 16; ++it) {
        const int seg = it * 512 + tid;
        const int row = seg >> 6, cs = seg & 63;
        const float4 lv = *(const float4*)(smb + seg * 16);
        float* gp = &fout[(am0 + p * 128 + row) * N + bn0 + cs * 4];
        float4 o = *(const float4*)gp;
        o.x += lv.x;
        o.y += lv.y;
        o.z += lv.z;
        o.w += lv.w;
        *(float4*)gp = o;
      }
    }
  }
}

// ------- control: 8-wave 256x256, BK=32, 4-slot ring, distance 2 (R4/R7) ----
template <int K, int N, bool GELU, bool SWZ>
__global__ __launch_bounds__(512, 2) void gemm8p(
    const __hip_bfloat16* __restrict__ A, const __hip_bfloat16* __restrict__ Bt,
    const float* __restrict__ bias, __hip_bfloat16* __restrict__ zout,
    float* __restrict__ fout, size_t am_base) {
  constexpr int NT = N / 256;
  constexpr int NKT = K / 32;
  __shared__ __attribute__((aligned(16))) __hip_bfloat16 lds[4][2][256 * 32];

  const int tid = threadIdx.x;
  const int lane = tid & 63;
  const int w = tid >> 6;
  const int wm = w >> 2, wn = w & 3;

  const int cpx = gridDim.x >> 3;
  const int bid = (blockIdx.x & 7) * cpx + (blockIdx.x >> 3);
  const int tm = bid / NT, tn = bid - tm * NT;
  const size_t am0 = am_base + (size_t)tm * 256;
  const int bn0 = tn * 256;

  const int r0 = tid >> 2;
  const int ks0 = SWZ ? ((tid & 3) ^ ((tid >> 2) & 3) ^ ((tid >> 4) & 3))
                      : (tid & 3);
  const __hip_bfloat16* aP0 = A + (am0 + r0) * K + ks0 * 8;
  const __hip_bfloat16* aP1 = aP0 + (size_t)128 * K;
  const __hip_bfloat16* bP0 = Bt + (size_t)(bn0 + r0) * K + ks0 * 8;
  const __hip_bfloat16* bP1 = bP0 + (size_t)128 * K;
  const int lo0 = (w * 64) * 8;
  const int lo1 = (512 + w * 64) * 8;

#define STAGE_A(sl, kt)                            \
  do {                                             \
    load_lds16(aP0 + (kt) * 32, &lds[sl][0][lo0]); \
    load_lds16(aP1 + (kt) * 32, &lds[sl][0][lo1]); \
  } while (0)
#define STAGE_B(sl, kt)                            \
  do {                                             \
    load_lds16(bP0 + (kt) * 32, &lds[sl][1][lo0]); \
    load_lds16(bP1 + (kt) * 32, &lds[sl][1][lo1]); \
  } while (0)

  f32x4 acc[8][4] = {};
  const int fr = lane & 15;
  const int kgs = (SWZ ? ((lane >> 4) ^ (lane & 3) ^ ((lane >> 2) & 3))
                       : (lane >> 4)) * 8;

  STAGE_A(0, 0);
  STAGE_B(0, 0);
  STAGE_A(1, 1);
  STAGE_B(1, 1);

  for (int t = 0; t < NKT; ++t) {
    if (t + 1 < NKT)
      asm volatile("s_waitcnt vmcnt(4)" ::: "memory");
    else
      asm volatile("s_waitcnt vmcnt(0)" ::: "memory");
    __builtin_amdgcn_s_barrier();

    const int sl = t & 3;
    const int s2 = (t + 2) & 3;
    const bool pf = (t + 2) < NKT;
    const __hip_bfloat16* As = lds[sl][0];
    const __hip_bfloat16* Bs = lds[sl][1];

    if (pf) STAGE_A(s2, t + 2);
    bf16x8 bfv[4];
#pragma unroll
    for (int n = 0; n < 4; ++n)
      bfv[n] = *(const bf16x8*)(Bs + (wn * 64 + n * 16 + fr) * 32 + kgs);
    bf16x8 af[4];
#pragma unroll
    for (int m = 0; m < 4; ++m)
      af[m] = *(const bf16x8*)(As + (wm * 128 + m * 16 + fr) * 32 + kgs);
    __builtin_amdgcn_s_setprio(1);
#pragma unroll
    for (int m = 0; m < 4; ++m)
#pragma unroll
      for (int n = 0; n < 4; ++n)
        acc[m][n] = __builtin_amdgcn_mfma_f32_16x16x32_bf16(af[m], bfv[n],
                                                            acc[m][n], 0, 0, 0);
    __builtin_amdgcn_s_setprio(0);
    __builtin_amdgcn_s_barrier();

    if (pf) STAGE_B(s2, t + 2);
#pragma unroll
    for (int m = 0; m < 4; ++m)
      af[m] = *(const bf16x8*)(As + (wm * 128 + (m + 4) * 16 + fr) * 32 + kgs);
    __builtin_amdgcn_s_setprio(1);
#pragma unroll
    for (int m = 0; m < 4; ++m)
#pragma unroll
      for (int n = 0; n < 4; ++n)
        acc[m + 4][n] = __builtin_amdgcn_mfma_f32_16x16x32_bf16(
            af[m], bfv[n], acc[m + 4][n], 0, 0, 0);
    __builtin_amdgcn_s_setprio(0);
  }
#undef STAGE_A
#undef STAGE_B

  epilogue<N, GELU>(acc, (char*)&lds[0][0][0], tid, lane, wm, wn, am0, bn0,
                    bias, zout, fout);
}

// ------- variant B: 8-wave 256x256, BK=64, 2-slot classic dbuf -------------
// {stage t+1 -> other slot; ds_read + 64 MFMA from cur; vmcnt(0); barrier}.
// One barrier + one (fully-covered) vmcnt(0) per 64-k. 128B row stride needs
// the XOR swizzle: LDS[row][q] holds k-seg q^(row&7) (pre-swizzled source,
// linear dest, swizzled read — rule #21).
template <int K, int N, bool GELU>
__global__ __launch_bounds__(512, 1) void gemm2s(
    const __hip_bfloat16* __restrict__ A, const __hip_bfloat16* __restrict__ Bt,
    const float* __restrict__ bias, __hip_bfloat16* __restrict__ zout,
    float* __restrict__ fout, size_t am_base) {
  constexpr int NT = N / 256;
  constexpr int NKT = K / 64;
  __shared__ __attribute__((aligned(16))) __hip_bfloat16 sm[2][2][256 * 64];

  const int tid = threadIdx.x;
  const int lane = tid & 63;
  const int w = tid >> 6;
  const int wm = w >> 2, wn = w & 3;

  const int cpx = gridDim.x >> 3;
  const int bid = (blockIdx.x & 7) * cpx + (blockIdx.x >> 3);
  const int tm = bid / NT, tn = bid - tm * NT;
  const size_t am0 = am_base + (size_t)tm * 256;
  const int bn0 = tn * 256;

  // staging: 4 segs/matrix/thread: s = tid + 512*i -> row = (tid>>3)+64*i,
  // phys q = tid&7; source k-seg = q ^ (row&7) (row&7 invariant in i)
  const int r0 = tid >> 3;
  const int pq = tid & 7;
  const int sks = pq ^ (r0 & 7);
  const __hip_bfloat16* pA = A + (am0 + r0) * K + sks * 8;
  const __hip_bfloat16* pB = Bt + (size_t)(bn0 + r0) * K + sks * 8;

#define STG2(sl, kt)                                                  \
  do {                                                                \
    _Pragma("unroll") for (int i = 0; i < 4; ++i)                     \
        load_lds16(pA + (size_t)(kt) * 64 + (size_t)(64 * i) * K,     \
                   &sm[sl][0][(512 * i + w * 64) * 8]);               \
    _Pragma("unroll") for (int i = 0; i < 4; ++i)                     \
        load_lds16(pB + (size_t)(kt) * 64 + (size_t)(64 * i) * K,     \
                   &sm[sl][1][(512 * i + w * 64) * 8]);               \
  } while (0)

  // read: row = base16 + fr -> row&7 = fr&7; phys seg = kseg ^ (fr&7)
  const int fr = lane & 15, kq = lane >> 4;
  const int qb0 = ((kq) ^ (fr & 7)) * 16;      // kh=0: ksegs 0..3
  const int qb1 = ((4 + kq) ^ (fr & 7)) * 16;  // kh=1: ksegs 4..7

  f32x4 acc[8][4] = {};

  STG2(0, 0);
  asm volatile("s_waitcnt vmcnt(0)" ::: "memory");
  __builtin_amdgcn_s_barrier();

  for (int t = 0; t < NKT; ++t) {
    const int d = t & 1, dn = d ^ 1;
    if (t + 1 < NKT) STG2(dn, t + 1);
    const char* As = (const char*)&sm[d][0][0];
    const char* Bs = (const char*)&sm[d][1][0];
#pragma unroll
    for (int kh = 0; kh < 2; ++kh) {
      const int qb = kh ? qb1 : qb0;
      bf16x8 bfv[4], af[8];
#pragma unroll
      for (int n = 0; n < 4; ++n)
        bfv[n] = *(const bf16x8*)(Bs + (wn * 64 + n * 16 + fr) * 128 + qb);
#pragma unroll
      for (int m = 0; m < 8; ++m)
        af[m] = *(const bf16x8*)(As + (wm * 128 + m * 16 + fr) * 128 + qb);
      __builtin_amdgcn_s_setprio(1);
#pragma unroll
      for (int m = 0; m < 8; ++m)
#pragma unroll
        for (int n = 0; n < 4; ++n)
          acc[m][n] = __builtin_amdgcn_mfma_f32_16x16x32_bf16(af[m], bfv[n],
                                                              acc[m][n], 0, 0,
                                                              0);
      __builtin_amdgcn_s_setprio(0);
    }
    // wait own t+1 stage (issued ~2500cy ago, covered) + publish block-wide
    asm volatile("s_waitcnt vmcnt(0)" ::: "memory");
    __builtin_amdgcn_s_barrier();
  }
#undef STG2

  epilogue<N, GELU>(acc, (char*)&sm[0][0][0], tid, lane, wm, wn, am0, bn0,
                    bias, zout, fout);
}

extern "C" void kernel_launch(void* const* d_in, const int* in_sizes, int n_in,
                              void* d_out, int out_size, void* d_ws,
                              size_t ws_size, hipStream_t stream) {
  const float* x = (const float*)d_in[0];
  const float* n1g = (const float*)d_in[1];
  const float* n1b = (const float*)d_in[2];
  const float* wsp = (const float*)d_in[3];
  const float* n2g = (const float*)d_in[4];
  const float* n2b = (const float*)d_in[5];
  const float* w1 = (const float*)d_in[6];
  const float* b1 = (const float*)d_in[7];
  const float* w2 = (const float*)d_in[8];
  const float* b2 = (const float*)d_in[9];
  float* out = (float*)d_out;

  __hip_bfloat16* ybuf = (__hip_bfloat16*)d_ws;
  __hip_bfloat16* zbuf = ybuf + (size_t)MROWS * CDIM;
  __hip_bfloat16* w1t = zbuf + (size_t)MROWS * HID;
  __hip_bfloat16* w2t = w1t + (size_t)CDIM * HID;

  cvt_t<CDIM, HID><<<(CDIM / 64) * (HID / 64), 256, 0, stream>>>(w1, w1t);
  cvt_t<HID, CDIM><<<(HID / 64) * (CDIM / 64), 256, 0, stream>>>(w2, w2t);
  fused_pre<<<2048, 256, 0, stream>>>(x, n1g, n1b, wsp, n2g, n2b, out, ybuf);

  // A/B ablation: M-split halves, per-dispatch rocprof rows.
  // grids: 196*8 = 1568, 196*2 = 392; both % 8 == 0.
  gemm8p<CDIM, HID, true, true>
      <<<(MHALF / 256) * (HID / 256), 512, 0, stream>>>(ybuf, w1t, b1, zbuf,
                                                        nullptr, 0);
  gemm8p<CDIM, HID, true, false>
      <<<(MHALF / 256) * (HID / 256), 512, 0, stream>>>(ybuf, w1t, b1, zbuf,
                                                        nullptr, MHALF);
  gemm8p<HID, CDIM, false, true>
      <<<(MHALF / 256) * (CDIM / 256), 512, 0, stream>>>(zbuf, w2t, b2, nullptr,
                                                         out, 0);
  gemm2s<HID, CDIM, false>
      <<<(MHALF / 256) * (CDIM / 256), 512, 0, stream>>>(zbuf, w2t, b2, nullptr,
                                                         out, MHALF);
}

// Round 9
// 921.700 us; speedup vs baseline: 1.0625x; 1.0625x over previous
//
#include <hip/hip_runtime.h>
#include <hip/hip_bf16.h>

// SwinMLP block, fp32 in/out, bf16 MFMA internals.
//   1) cvt_t: w1 -> w1t (bf16, NxK), w2 -> w2t (bf16, NxK)
//   2) fused_pre: LN1 + per-head 32x32 spatial mix + residual -> x2 (d_out)
//      + LN2(x2) -> y (bf16, ws)   [2 rows/iter: 2 barriers/row]
//   3) gemmpp<512,2048,GELU>: z = gelu(y @ w1 + b1)
//   4) gemmpp<2048,512,RES>:  d_out = x2 + z @ w2 + b2
//
// R8 findings: 128KB LDS => 1 block/CU (Occ 21% = 8 waves); K-loop is
// burst-serialized {LDS-read ; MFMA} per tile (~4.9Kcy vs 1.24K MFMA).
// gemm2s (drain-0, fewer barriers) lost; swizzle null (BK=32 64B rows are
// bank-optimal). R9: m201 mechanic on the proven 4-slot ring — per-phase
// READ-AHEAD: ds_reads of the NEXT MFMA cluster issue under the CURRENT
// cluster; next-tile frags read one tile early (certified by mid-tile
// vmcnt(2)+barrier). 2 barriers + 1 counted vmcnt per tile, no lgkm asm.

typedef __bf16 bf16x8 __attribute__((ext_vector_type(8)));
typedef float f32x4 __attribute__((ext_vector_type(4)));

constexpr int CDIM = 512;
constexpr int HID = 2048;
constexpr int MROWS = 32 * 3136;  // 100352 = 392 * 256
constexpr float LN_EPS = 1e-5f;

static __device__ __forceinline__ float gelu_tanh(float x) {
  const float u = 0.7978845608028654f * fmaf(0.044715f * x * x, x, x);
  const float e = __expf(2.0f * u);
  return 0.5f * x * (2.0f - 2.0f / (e + 1.0f));
}

static __device__ __forceinline__ void load_lds16(const void* g, void* l) {
  __builtin_amdgcn_global_load_lds((__attribute__((address_space(1))) void*)g,
                                   (__attribute__((address_space(3))) void*)l,
                                   16, 0, 0);
}

// ---- transpose fp32 src[KD][ND] -> bf16 dst[ND][KD], 64x64 LDS tiles ----
template <int KD, int ND>
__global__ __launch_bounds__(256) void cvt_t(const float* __restrict__ src,
                                             __hip_bfloat16* __restrict__ dst) {
  __shared__ float tl[64][65];
  const int t = threadIdx.x;
  constexpr int NTN = ND / 64;
  const int k0 = (blockIdx.x / NTN) * 64;
  const int n0 = (blockIdx.x % NTN) * 64;
  const int c4 = (t & 15) * 4;
  const int r = t >> 4;
#pragma unroll
  for (int j = 0; j < 4; ++j) {
    const int kk = r + j * 16;
    const float4 v = *(const float4*)&src[(size_t)(k0 + kk) * ND + n0 + c4];
    tl[c4 + 0][kk] = v.x;
    tl[c4 + 1][kk] = v.y;
    tl[c4 + 2][kk] = v.z;
    tl[c4 + 3][kk] = v.w;
  }
  __syncthreads();
#pragma unroll
  for (int j = 0; j < 4; ++j) {
    const int nn = r + j * 16;
    __hip_bfloat16 o[4];
#pragma unroll
    for (int c = 0; c < 4; ++c) o[c] = __float2bfloat16(tl[nn][c4 + c]);
    *(uint2*)&dst[(size_t)(n0 + nn) * KD + k0 + c4] = *(const uint2*)o;
  }
}

// -------- fused LN1 + spatial mix + residual + LN2, 2 rows / iteration ------
__global__ __launch_bounds__(256) void fused_pre(
    const float* __restrict__ x, const float* __restrict__ g1,
    const float* __restrict__ b1, const float* __restrict__ wsp,
    const float* __restrict__ g2, const float* __restrict__ b2,
    float* __restrict__ x2out, __hip_bfloat16* __restrict__ yout) {
  __shared__ float lnbuf[2][CDIM];
  __shared__ float red[16];

  const int t = threadIdx.x;
  const int lane = t & 63;
  const int w = t >> 6;
  const int c0 = 2 * t;  // cols c0, c0+1 (same head); shared by both rows
  const int hd = c0 >> 5, e0 = c0 & 31;

  float wc0[32], wc1[32];
#pragma unroll
  for (int d = 0; d < 32; ++d) {
    const float2 wv = *(const float2*)&wsp[(hd * 32 + d) * 32 + e0];
    wc0[d] = wv.x;
    wc1[d] = wv.y;
  }
  const float2 g1v = *(const float2*)&g1[c0];
  const float2 b1v = *(const float2*)&b1[c0];
  const float2 g2v = *(const float2*)&g2[c0];
  const float2 b2v = *(const float2*)&b2[c0];

  for (int rp = blockIdx.x; rp < MROWS / 2; rp += gridDim.x) {
    const size_t ra = (size_t)rp * 2, rb = ra + 1;
    const float2 xa = *(const float2*)&x[ra * CDIM + c0];
    const float2 xb = *(const float2*)&x[rb * CDIM + c0];

    float sa = xa.x + xa.y, qa = xa.x * xa.x + xa.y * xa.y;
    float sb = xb.x + xb.y, qb = xb.x * xb.x + xb.y * xb.y;
#pragma unroll
    for (int off = 32; off; off >>= 1) {
      sa += __shfl_down(sa, off);
      qa += __shfl_down(qa, off);
      sb += __shfl_down(sb, off);
      qb += __shfl_down(qb, off);
    }
    if (lane == 0) {
      red[w * 4 + 0] = sa;
      red[w * 4 + 1] = qa;
      red[w * 4 + 2] = sb;
      red[w * 4 + 3] = qb;
    }
    __syncthreads();  // B1
    sa = red[0] + red[4] + red[8] + red[12];
    qa = red[1] + red[5] + red[9] + red[13];
    sb = red[2] + red[6] + red[10] + red[14];
    qb = red[3] + red[7] + red[11] + red[15];
    float mua = sa * (1.0f / CDIM), mub = sb * (1.0f / CDIM);
    float rsa = rsqrtf(qa * (1.0f / CDIM) - mua * mua + LN_EPS);
    float rsb = rsqrtf(qb * (1.0f / CDIM) - mub * mub + LN_EPS);
    lnbuf[0][c0] = (xa.x - mua) * rsa * g1v.x + b1v.x;
    lnbuf[0][c0 + 1] = (xa.y - mua) * rsa * g1v.y + b1v.y;
    lnbuf[1][c0] = (xb.x - mub) * rsb * g1v.x + b1v.x;
    lnbuf[1][c0 + 1] = (xb.y - mub) * rsb * g1v.y + b1v.y;
    __syncthreads();  // B2

    float ha0 = 0.f, ha1 = 0.f, hb0 = 0.f, hb1 = 0.f;
#pragma unroll
    for (int d = 0; d < 32; ++d) {
      const float la = lnbuf[0][hd * 32 + d];
      const float lb = lnbuf[1][hd * 32 + d];
      ha0 = fmaf(la, wc0[d], ha0);
      ha1 = fmaf(la, wc1[d], ha1);
      hb0 = fmaf(lb, wc0[d], hb0);
      hb1 = fmaf(lb, wc1[d], hb1);
    }
    const float a0 = xa.x + ha0, a1 = xa.y + ha1;
    const float b0 = xb.x + hb0, b1r = xb.y + hb1;
    float2 av;
    av.x = a0;
    av.y = a1;
    *(float2*)&x2out[ra * CDIM + c0] = av;
    av.x = b0;
    av.y = b1r;
    *(float2*)&x2out[rb * CDIM + c0] = av;

    sa = a0 + a1;
    qa = a0 * a0 + a1 * a1;
    sb = b0 + b1r;
    qb = b0 * b0 + b1r * b1r;
#pragma unroll
    for (int off = 32; off; off >>= 1) {
      sa += __shfl_down(sa, off);
      qa += __shfl_down(qa, off);
      sb += __shfl_down(sb, off);
      qb += __shfl_down(qb, off);
    }
    if (lane == 0) {
      red[w * 4 + 0] = sa;
      red[w * 4 + 1] = qa;
      red[w * 4 + 2] = sb;
      red[w * 4 + 3] = qb;
    }
    __syncthreads();  // B3
    sa = red[0] + red[4] + red[8] + red[12];
    qa = red[1] + red[5] + red[9] + red[13];
    sb = red[2] + red[6] + red[10] + red[14];
    qb = red[3] + red[7] + red[11] + red[15];
    mua = sa * (1.0f / CDIM);
    mub = sb * (1.0f / CDIM);
    rsa = rsqrtf(qa * (1.0f / CDIM) - mua * mua + LN_EPS);
    rsb = rsqrtf(qb * (1.0f / CDIM) - mub * mub + LN_EPS);
    __hip_bfloat162 yv;
    yv.x = __float2bfloat16((a0 - mua) * rsa * g2v.x + b2v.x);
    yv.y = __float2bfloat16((a1 - mua) * rsa * g2v.y + b2v.y);
    *(__hip_bfloat162*)&yout[ra * CDIM + c0] = yv;
    yv.x = __float2bfloat16((b0 - mub) * rsb * g2v.x + b2v.x);
    yv.y = __float2bfloat16((b1r - mub) * rsb * g2v.y + b2v.y);
    *(__hip_bfloat162*)&yout[rb * CDIM + c0] = yv;
    __syncthreads();  // B4 (lnbuf/red reuse)
  }
}

// ---- shared epilogue: LDS bounce, full-line coalesced writes (R7-verified) --
template <int N, bool GELU>
static __device__ __forceinline__ void epilogue(const f32x4 (&acc)[8][4],
                                                char* smb, int tid, int lane,
                                                int wm, int wn, size_t am0,
                                                int bn0,
                                                const float* __restrict__ bias,
                                                __hip_bfloat16* __restrict__ zout,
                                                float* __restrict__ fout) {
  const int cr = (lane >> 4) * 4;
  const int cc = lane & 15;
  if constexpr (GELU) {
    __syncthreads();
    __hip_bfloat16* ot = (__hip_bfloat16*)smb;
#pragma unroll
    for (int n = 0; n < 4; ++n) {
      const int col = wn * 64 + n * 16 + cc;
      const float bv = bias[bn0 + col];
#pragma unroll
      for (int m = 0; m < 8; ++m) {
        const int row = wm * 128 + m * 16 + cr;
#pragma unroll
        for (int j = 0; j < 4; ++j)
          ot[(row + j) * 256 + col] =
              __float2bfloat16(gelu_tanh(acc[m][n][j] + bv));
      }
    }
    __syncthreads();
#pragma unroll
    for (int it = 0; it < 16; ++it) {
      const int seg = it * 512 + tid;
      const int row = seg >> 5, cs = seg & 31;
      const uint4 v = *(const uint4*)(smb + seg * 16);
      *(uint4*)&zout[(am0 + row) * N + bn0 + cs * 8] = v;
    }
  } else {
    float* ot = (float*)smb;
#pragma unroll
    for (int p = 0; p < 2; ++p) {
      __syncthreads();
      if (wm == p) {
#pragma unroll
        for (int n = 0; n < 4; ++n) {
          const int col = wn * 64 + n * 16 + cc;
          const float bv = bias[bn0 + col];
#pragma unroll
          for (int m = 0; m < 8; ++m) {
            const int rl = m * 16 + cr;
#pragma unroll
            for (int j = 0; j < 4; ++j)
              ot[(rl + j) * 256 + col] = acc[m][n][j] + bv;
          }
        }
      }
      __syncthreads();
#pragma unroll
      for (int it = 0; it < 16; ++it) {
        const int seg = it * 512 + tid;
        const int row = seg >> 6, cs = seg & 63;
        const float4 lv = *(const float4*)(smb + seg * 16);
        float* gp = &fout[(am0 + p * 128 + row) * N + bn0 + cs * 4];
        float4 o = *(const float4*)gp;
        o.x += lv.x;
        o.y += lv.y;
        o.z += lv.z;
        o.w += lv.w;
        *(float4*)gp = o;
      }
    }
  }
}

// ---- 8-wave 256x256, BK=32, 4-slot ring + per-phase READ-AHEAD (m201) ----
// Per tile t (slot sl=t&3):
//  P0: stage A(t+2); MFMA m0-3 (regs preloaded last tile); ds_read A4-7(t)
//  mid: vmcnt(2) [certifies t+1's 4 stages] + s_barrier
//  P1: stage B(t+2); MFMA m4-7; ds_read A0-3(t+1)+B(t+1) from slot (t+1)&3
//  end: s_barrier
// Ledger: 4 outstanding at tile top (invariant); slot X written at X-2,
// prior content last read at X-3.P0 -> barrier-separated. No swizzle
// (BK=32 rows are 64B: fragment b128 reads already bank-optimal, R8-null).
template <int K, int N, bool GELU>
__global__ __launch_bounds__(512) void gemmpp(
    const __hip_bfloat16* __restrict__ A, const __hip_bfloat16* __restrict__ Bt,
    const float* __restrict__ bias, __hip_bfloat16* __restrict__ zout,
    float* __restrict__ fout) {
  constexpr int NT = N / 256;
  constexpr int NKT = K / 32;
  __shared__ __attribute__((aligned(16))) __hip_bfloat16 lds[4][2][256 * 32];

  const int tid = threadIdx.x;
  const int lane = tid & 63;
  const int w = tid >> 6;
  const int wm = w >> 2, wn = w & 3;  // wave tile 128x64 (2M x 4N)

  // T1: XCD-aware bijective swizzle (grid % 8 == 0 by construction)
  const int cpx = gridDim.x >> 3;
  const int bid = (blockIdx.x & 7) * cpx + (blockIdx.x >> 3);
  const int tm = bid / NT, tn = bid - tm * NT;
  const size_t am0 = (size_t)tm * 256;
  const int bn0 = tn * 256;

  // staging: thread stages segs tid (rows 0..127) and tid+512 (rows 128..255)
  const int r0 = tid >> 2;
  const int q0 = tid & 3;
  const __hip_bfloat16* aP0 = A + (am0 + r0) * K + q0 * 8;
  const __hip_bfloat16* aP1 = aP0 + (size_t)128 * K;
  const __hip_bfloat16* bP0 = Bt + (size_t)(bn0 + r0) * K + q0 * 8;
  const __hip_bfloat16* bP1 = bP0 + (size_t)128 * K;
  const int lo0 = (w * 64) * 8;
  const int lo1 = (512 + w * 64) * 8;

#define STAGE_A(sl, kt)                            \
  do {                                             \
    load_lds16(aP0 + (kt) * 32, &lds[sl][0][lo0]); \
    load_lds16(aP1 + (kt) * 32, &lds[sl][0][lo1]); \
  } while (0)
#define STAGE_B(sl, kt)                            \
  do {                                             \
    load_lds16(bP0 + (kt) * 32, &lds[sl][1][lo0]); \
    load_lds16(bP1 + (kt) * 32, &lds[sl][1][lo1]); \
  } while (0)

  // fragment geometry: row*64B + (lane>>4)*16B, row = base + fr
  const int fr = lane & 15;
  const int kb = (lane >> 4) * 16;  // bytes

#define LD_A03(sl)                                                          \
  do {                                                                      \
    _Pragma("unroll") for (int m = 0; m < 4; ++m) a03[m] =                  \
        *(const bf16x8*)((const char*)&lds[sl][0][0] +                      \
                         (wm * 128 + m * 16 + fr) * 64 + kb);               \
  } while (0)
#define LD_A47(sl)                                                          \
  do {                                                                      \
    _Pragma("unroll") for (int m = 0; m < 4; ++m) a47[m] =                  \
        *(const bf16x8*)((const char*)&lds[sl][0][0] +                      \
                         (wm * 128 + (m + 4) * 16 + fr) * 64 + kb);         \
  } while (0)
#define LD_B(sl)                                                            \
  do {                                                                      \
    _Pragma("unroll") for (int n = 0; n < 4; ++n) bf[n] =                   \
        *(const bf16x8*)((const char*)&lds[sl][1][0] +                      \
                         (wn * 64 + n * 16 + fr) * 64 + kb);                \
  } while (0)

  f32x4 acc[8][4] = {};
  bf16x8 a03[4], a47[4], bf[4];

  // prologue: tiles 0,1 -> slots 0,1 (8 loads); certify tile 0; preload regs
  STAGE_A(0, 0);
  STAGE_B(0, 0);
  STAGE_A(1, 1);
  STAGE_B(1, 1);
  asm volatile("s_waitcnt vmcnt(4)" ::: "memory");
  __builtin_amdgcn_s_barrier();
  LD_A03(0);
  LD_B(0);

  for (int t = 0; t < NKT; ++t) {
    const int sl = t & 3, sl1 = (t + 1) & 3, sl2 = (t + 2) & 3;
    const bool pf2 = (t + 2) < NKT, pf1 = (t + 1) < NKT;

    // ---- P0 ----
    if (pf2) STAGE_A(sl2, t + 2);
    __builtin_amdgcn_s_setprio(1);
#pragma unroll
    for (int m = 0; m < 4; ++m)
#pragma unroll
      for (int n = 0; n < 4; ++n)
        acc[m][n] = __builtin_amdgcn_mfma_f32_16x16x32_bf16(a03[m], bf[n],
                                                            acc[m][n], 0, 0, 0);
    __builtin_amdgcn_s_setprio(0);
    LD_A47(sl);  // for P1's cluster (issues under the MFMA drain)

    if (pf2)
      asm volatile("s_waitcnt vmcnt(2)" ::: "memory");  // t+1 resident
    else
      asm volatile("s_waitcnt vmcnt(0)" ::: "memory");
    __builtin_amdgcn_s_barrier();

    // ---- P1 ----
    if (pf2) STAGE_B(sl2, t + 2);
    __builtin_amdgcn_s_setprio(1);
#pragma unroll
    for (int m = 0; m < 4; ++m)
#pragma unroll
      for (int n = 0; n < 4; ++n)
        acc[m + 4][n] = __builtin_amdgcn_mfma_f32_16x16x32_bf16(
            a47[m], bf[n], acc[m + 4][n], 0, 0, 0);
    __builtin_amdgcn_s_setprio(0);
    if (pf1) {  // read-ahead next tile's first cluster + B
      LD_A03(sl1);
      LD_B(sl1);
    }
    __builtin_amdgcn_s_barrier();
  }
#undef STAGE_A
#undef STAGE_B
#undef LD_A03
#undef LD_A47
#undef LD_B

  epilogue<N, GELU>(acc, (char*)&lds[0][0][0], tid, lane, wm, wn, am0, bn0,
                    bias, zout, fout);
}

extern "C" void kernel_launch(void* const* d_in, const int* in_sizes, int n_in,
                              void* d_out, int out_size, void* d_ws,
                              size_t ws_size, hipStream_t stream) {
  const float* x = (const float*)d_in[0];
  const float* n1g = (const float*)d_in[1];
  const float* n1b = (const float*)d_in[2];
  const float* wsp = (const float*)d_in[3];
  const float* n2g = (const float*)d_in[4];
  const float* n2b = (const float*)d_in[5];
  const float* w1 = (const float*)d_in[6];
  const float* b1 = (const float*)d_in[7];
  const float* w2 = (const float*)d_in[8];
  const float* b2 = (const float*)d_in[9];
  float* out = (float*)d_out;

  __hip_bfloat16* ybuf = (__hip_bfloat16*)d_ws;
  __hip_bfloat16* zbuf = ybuf + (size_t)MROWS * CDIM;
  __hip_bfloat16* w1t = zbuf + (size_t)MROWS * HID;
  __hip_bfloat16* w2t = w1t + (size_t)CDIM * HID;

  cvt_t<CDIM, HID><<<(CDIM / 64) * (HID / 64), 256, 0, stream>>>(w1, w1t);
  cvt_t<HID, CDIM><<<(HID / 64) * (CDIM / 64), 256, 0, stream>>>(w2, w2t);
  fused_pre<<<2048, 256, 0, stream>>>(x, n1g, n1b, wsp, n2g, n2b, out, ybuf);
  // grids: 392*8 = 3136 and 392*2 = 784, both % 8 == 0
  gemmpp<CDIM, HID, true><<<(MROWS / 256) * (HID / 256), 512, 0, stream>>>(
      ybuf, w1t, b1, zbuf, nullptr);
  gemmpp<HID, CDIM, false><<<(MROWS / 256) * (CDIM / 256), 512, 0, stream>>>(
      zbuf, w2t, b2, nullptr, out);
}